// Round 3
// baseline (94.737 us; speedup 1.0000x reference)
//
#include <hip/hip_runtime.h>

// Problem constants (match reference)
constexpr int cB = 8;
constexpr int cN = 4096;
constexpr int cD = 1024;   // IN_FEATURES
constexpr int cH = 1792;   // HIDDEN_DIM

constexpr int NS = 32;          // K1: x-row splits per batch (128 rows/block)
constexpr int CH = 16;          // K23: h-values per block
constexpr int HS = cH / CH;     // 112 blocks

// Fixed-point scales (deterministic integer accumulation)
constexpr float S1  = 16777216.0f;             // 2^24  for xsum
constexpr double S1D = 1.0 / 16777216.0;
constexpr float S2  = 281474976710656.0f;      // 2^48  for v
constexpr double S2D = 1.0 / 281474976710656.0;
constexpr float S3  = 17179869184.0f;          // 2^34  for c
constexpr double S3D = 1.0 / 17179869184.0;

typedef unsigned long long ull;

// Workspace (int64): xsum[8192] | v[8192] | c[8]
constexpr size_t OFF_XSUM = 0;
constexpr size_t OFF_V    = 8192;
constexpr size_t OFF_CV   = 16384;
constexpr size_t WS_I64   = 16392;

__device__ __forceinline__ float dot4(float4 a, float4 b) {
    return a.x * b.x + a.y * b.y + a.z * b.z + a.w * b.w;
}
__device__ __forceinline__ void atomic_i64(ull* p, float val) {
    long long q = llrintf(val);
    atomicAdd(p, (ull)q);   // two's-complement wrap == exact signed sum
}
__device__ __forceinline__ float dec(const ull* p, double inv) {
    return (float)((double)(long long)(*p) * inv);
}

// ---------------------------------------------------------------------------
// K1: xsum[b][d] += sum over this block's 128 rows of x[b]   (int64 atomics)
// grid = B*NS = 256 blocks, 512 threads. Thread (half,col) sums rows half+2r.
__global__ __launch_bounds__(512) void K1(const float* __restrict__ x,
                                          ull* __restrict__ xsum_i) {
    int bid = blockIdx.x;
    int b = bid / NS, ns = bid % NS;
    int t = threadIdx.x;
    int half = t >> 8;        // 0/1: row parity
    int col  = t & 255;       // float4 column
    const float4* xp = (const float4*)(x + ((size_t)b * cN + (size_t)ns * 128 + half) * cD);
    float4 acc = make_float4(0.f, 0.f, 0.f, 0.f);
#pragma unroll 8
    for (int r = 0; r < 64; ++r) {
        float4 v = xp[(size_t)(2 * r) * (cD / 4) + col];
        acc.x += v.x; acc.y += v.y; acc.z += v.z; acc.w += v.w;
    }
    ull* dst = xsum_i + (size_t)b * cD + 4 * col;
    atomic_i64(dst + 0, acc.x * S1);
    atomic_i64(dst + 1, acc.y * S1);
    atomic_i64(dst + 2, acc.z * S1);
    atomic_i64(dst + 3, acc.w * S1);
}

// ---------------------------------------------------------------------------
// K23: per block: 16 h-values; wave w = batch b.
//   ksum[b,h] = xsum[b]·Wk[h] + N*bk[h]  (in-register, wave broadcast)
//   v[b,d]    += Wq[h,d]*ksum            (int64 atomics)
//   c[b]      += bq[h]*ksum              (int64 atomic, lane 0)
__global__ __launch_bounds__(512) void K23(const ull* __restrict__ xsum_i,
                                           const float* __restrict__ Wk,
                                           const float* __restrict__ bk,
                                           const float* __restrict__ Wq,
                                           const float* __restrict__ bq,
                                           ull* __restrict__ v_i,
                                           ull* __restrict__ c_i) {
    int w = threadIdx.x >> 6, l = threadIdx.x & 63;
    int b = w;
    int h0 = blockIdx.x * CH;

    // decode xsum[b] fragment (16 floats/lane, coalesced 32B/lane)
    float4 xr[4];
#pragma unroll
    for (int j = 0; j < 4; ++j) {
        const ull* p = xsum_i + (size_t)b * cD + 4 * (l + 64 * j);
        xr[j].x = dec(p + 0, S1D);
        xr[j].y = dec(p + 1, S1D);
        xr[j].z = dec(p + 2, S1D);
        xr[j].w = dec(p + 3, S1D);
    }

    float4 vacc[4];
#pragma unroll
    for (int j = 0; j < 4; ++j) vacc[j] = make_float4(0.f, 0.f, 0.f, 0.f);
    float cacc = 0.f;

    for (int i = 0; i < CH; i += 2) {  // 2-way interleave: independent reduce chains
        int ha = h0 + i, hb = h0 + i + 1;
        const float4* wka = (const float4*)(Wk + (size_t)ha * cD);
        const float4* wkb = (const float4*)(Wk + (size_t)hb * cD);
        float pa = 0.f, pb = 0.f;
#pragma unroll
        for (int j = 0; j < 4; ++j) {
            pa += dot4(wka[l + 64 * j], xr[j]);
            pb += dot4(wkb[l + 64 * j], xr[j]);
        }
#pragma unroll
        for (int off = 32; off; off >>= 1) {
            pa += __shfl_xor(pa, off);
            pb += __shfl_xor(pb, off);
        }
        float ksa = pa + (float)cN * bk[ha];
        float ksb = pb + (float)cN * bk[hb];
        cacc += bq[ha] * ksa + bq[hb] * ksb;
        const float4* wqa = (const float4*)(Wq + (size_t)ha * cD);
        const float4* wqb = (const float4*)(Wq + (size_t)hb * cD);
#pragma unroll
        for (int j = 0; j < 4; ++j) {
            float4 qa = wqa[l + 64 * j];
            float4 qb = wqb[l + 64 * j];
            vacc[j].x = fmaf(qa.x, ksa, fmaf(qb.x, ksb, vacc[j].x));
            vacc[j].y = fmaf(qa.y, ksa, fmaf(qb.y, ksb, vacc[j].y));
            vacc[j].z = fmaf(qa.z, ksa, fmaf(qb.z, ksb, vacc[j].z));
            vacc[j].w = fmaf(qa.w, ksa, fmaf(qb.w, ksb, vacc[j].w));
        }
    }

#pragma unroll
    for (int j = 0; j < 4; ++j) {
        ull* dst = v_i + (size_t)b * cD + 4 * (l + 64 * j);
        atomic_i64(dst + 0, vacc[j].x * S2);
        atomic_i64(dst + 1, vacc[j].y * S2);
        atomic_i64(dst + 2, vacc[j].z * S2);
        atomic_i64(dst + 3, vacc[j].w * S2);
    }
    if (l == 0) atomic_i64(c_i + b, cacc * S3);
}

// ---------------------------------------------------------------------------
// K4: scores[b][n] = (x[b,n]·v[b] + c[b]) * (1/(N*sqrt(H)))
// 2048 blocks x 256 thr; 16 rows/block, 4/wave, 2-row-interleaved reduces.
__global__ __launch_bounds__(256) void K4(const float* __restrict__ x,
                                          const ull* __restrict__ v_i,
                                          const ull* __restrict__ c_i,
                                          float* __restrict__ out) {
    int row0 = blockIdx.x * 16;
    int b = row0 / cN;
    __shared__ float4 vs[cD / 4];
    int t = threadIdx.x;
    {   // decode v[b] into LDS
        const ull* p = v_i + (size_t)b * cD + 4 * t;
        vs[t] = make_float4(dec(p + 0, S2D), dec(p + 1, S2D),
                            dec(p + 2, S2D), dec(p + 3, S2D));
    }
    __syncthreads();
    int w = t >> 6, l = t & 63;
    float4 vv[4];
#pragma unroll
    for (int j = 0; j < 4; ++j) vv[j] = vs[l + 64 * j];
    float cb = dec(c_i + b, S3D);
    const float scale = (1.0f / 4096.0f) * (1.0f / sqrtf(1792.0f));
    int row = row0 + w * 4;
#pragma unroll
    for (int rp = 0; rp < 2; ++rp) {  // two pairs of rows, interleaved chains
        const float4* xa = (const float4*)(x + (size_t)(row + 2 * rp) * cD);
        const float4* xb = (const float4*)(x + (size_t)(row + 2 * rp + 1) * cD);
        float a0 = 0.f, a1 = 0.f;
#pragma unroll
        for (int j = 0; j < 4; ++j) {
            a0 += dot4(xa[l + 64 * j], vv[j]);
            a1 += dot4(xb[l + 64 * j], vv[j]);
        }
#pragma unroll
        for (int off = 32; off; off >>= 1) {
            a0 += __shfl_xor(a0, off);
            a1 += __shfl_xor(a1, off);
        }
        if (l == 0) {
            out[row + 2 * rp]     = (a0 + cb) * scale;
            out[row + 2 * rp + 1] = (a1 + cb) * scale;
        }
    }
}

// ---------------------------------------------------------------------------
extern "C" void kernel_launch(void* const* d_in, const int* in_sizes, int n_in,
                              void* d_out, int out_size, void* d_ws, size_t ws_size,
                              hipStream_t stream) {
    const float* x  = (const float*)d_in[0];
    const float* Wq = (const float*)d_in[1];
    const float* bq = (const float*)d_in[2];
    const float* Wk = (const float*)d_in[3];
    const float* bk = (const float*)d_in[4];
    float* out = (float*)d_out;

    ull* ws     = (ull*)d_ws;
    ull* xsum_i = ws + OFF_XSUM;
    ull* v_i    = ws + OFF_V;
    ull* c_i    = ws + OFF_CV;

    // zero the integer accumulators (tiny: 128 KB)
    hipMemsetAsync(d_ws, 0, WS_I64 * sizeof(ull), stream);

    // 1) xsum = sum_n x        (reads x once: 128 MiB, deterministic i64 atomics)
    K1<<<cB * NS, 512, 0, stream>>>(x, xsum_i);

    // 2+3) ksum in-register -> v, c   (reads Wk+Wq once: 14.6 MiB)
    K23<<<HS, 512, 0, stream>>>(xsum_i, Wk, bk, Wq, bq, v_i, c_i);

    // 4) scores = (x·v + c) * scale  (reads x again: 128 MiB, L3-warm)
    K4<<<(cB * cN) / 16, 256, 0, stream>>>(x, v_i, c_i, out);
}